// Round 15
// baseline (186.835 us; speedup 1.0000x reference)
//
#include <hip/hip_runtime.h>
#include <hip/hip_bf16.h>
#include <math.h>

typedef __attribute__((ext_vector_type(4))) float f32x4;
typedef __attribute__((ext_vector_type(4))) int   i32x4;
typedef __attribute__((ext_vector_type(8))) short short8;

#define NN 8192
#define LOG2E 1.44269504088896f

// f32 -> bf16 bits, round-to-nearest-even
__device__ __forceinline__ unsigned f2bfu(float x) {
    unsigned u = __float_as_uint(x);
    u += 0x7FFFu + ((u >> 16) & 1u);
    return u >> 16;
}
__device__ __forceinline__ float expneg(float s) {   // exp(-s)
    return __builtin_amdgcn_exp2f(-LOG2E * s);
}

// ---------------------------------------------------------------------------
// P1: h = x @ W1  [8192,500]@[500,64] with W1 staged in LDS. 1024 blocks x
// 8 rows (2 rows/wave) -> 16 waves/CU. Writes fsrc/edst = exp(-h.a halves).
// ---------------------------------------------------------------------------
#define P1_CHUNK 100
__global__ __launch_bounds__(256) void p1_kernel(
    const float* __restrict__ x, const float* __restrict__ W1,
    const float* __restrict__ a1, float* __restrict__ h,
    float* __restrict__ fsrc, float* __restrict__ edst)
{
    __shared__ float wtile[P1_CHUNK * 64];
    const int lane = threadIdx.x & 63;
    const int w    = threadIdx.x >> 6;
    const int r0   = blockIdx.x * 8 + w * 2;

    float acc[2];
    acc[0] = 0.f; acc[1] = 0.f;

    for (int c = 0; c < 5; ++c) {
        const int kb = c * P1_CHUNK;
        __syncthreads();
        for (int idx = threadIdx.x; idx < P1_CHUNK * 64; idx += 256)
            wtile[idx] = W1[kb * 64 + idx];
        __syncthreads();
        for (int kk = 0; kk < P1_CHUNK; kk += 4) {
            float w0 = wtile[(kk + 0) * 64 + lane];
            float w1 = wtile[(kk + 1) * 64 + lane];
            float w2 = wtile[(kk + 2) * 64 + lane];
            float w3 = wtile[(kk + 3) * 64 + lane];
#pragma unroll
            for (int r = 0; r < 2; ++r) {
                f32x4 xv = *(const f32x4*)(x + (size_t)(r0 + r) * 500 + kb + kk);
                acc[r] = fmaf(xv[0], w0, acc[r]);
                acc[r] = fmaf(xv[1], w1, acc[r]);
                acc[r] = fmaf(xv[2], w2, acc[r]);
                acc[r] = fmaf(xv[3], w3, acc[r]);
            }
        }
    }
    float a_s = a1[lane], a_d = a1[64 + lane];
#pragma unroll
    for (int r = 0; r < 2; ++r) {
        h[(size_t)(r0 + r) * 64 + lane] = acc[r];
        float ps = acc[r] * a_s, pd = acc[r] * a_d;
        for (int off = 32; off > 0; off >>= 1) {
            ps += __shfl_down(ps, off); pd += __shfl_down(pd, off);
        }
        if (lane == 0) {
            fsrc[r0 + r] = expneg(ps);
            edst[r0 + r] = expneg(pd);
        }
    }
}

// ---------------------------------------------------------------------------
// Swizzle f32 matrix into bf16 B-fragment order (layer-1 h -> hB):
// hB[kb][nb][lane][i] = bf16( h[kb*32 + (lane>>4)*8 + i][nb*16 + (lane&15)] )
// ---------------------------------------------------------------------------
__global__ __launch_bounds__(256) void swizzle_kernel(
    const float* __restrict__ h, short* __restrict__ hB,
    int nblk, int ncols, int total)
{
    int tid = blockIdx.x * 256 + threadIdx.x;
    if (tid >= total) return;
    int i  = tid & 7;
    int l  = (tid >> 3) & 63;
    int t2 = tid >> 9;
    int nb = t2 % nblk;
    int kb = t2 / nblk;
    int row = kb * 32 + (l >> 4) * 8 + i;
    int col = nb * 16 + (l & 15);
    float v = h[(size_t)row * ncols + col];
    hB[tid] = (short)f2bfu(v);
}

// ---------------------------------------------------------------------------
// FUSED GAT layer, 2 tiles/wave + DIRECT-FRAGMENT LOADS (no permute).
// Block = 8 waves x 512 thr, LB(512,4). Wave owns tiles mb0, mb0+1 x seg.
// Lane (fg=lane>>4, fr=lane&15) loads adj[row=fr][col=fg*8..+7] directly --
// same 16 full lines per k-step as r14's layout (memory-neutral), but the
// packed bf16 IS the MFMA A-fragment: zero shuffles. Es reads broadcast
// per 16-lane group; B-frag reads shared by both tiles.
// NO global stores in the loop (870 GB/s trap).
// ---------------------------------------------------------------------------
template <int NBLK>
__global__ __launch_bounds__(512, 4) void fused_kernel(
    const float* __restrict__ adj, const float* __restrict__ fsrc,
    const float* __restrict__ edst, const short* __restrict__ Bfrag,
    float* __restrict__ outp, float* __restrict__ normpart)
{
    __shared__ __align__(16) short Bs[16 * NBLK * 64 * 8];  // 64KB / 16KB
    __shared__ __align__(16) float Es[512];                 // 2KB
    const int tid  = threadIdx.x;
    const int lane = tid & 63;
    const int w    = tid >> 6;          // 0..7
    const int seg  = blockIdx.y;
    const int mb0  = blockIdx.x * 16 + w * 2;

    {
        const short8* src = (const short8*)(Bfrag) + (size_t)seg * (16 * NBLK * 64);
        short8* dst = (short8*)Bs;
#pragma unroll
        for (int j = 0; j < 2 * NBLK; ++j)
            dst[tid + 512 * j] = src[tid + 512 * j];
        Es[tid] = edst[seg * 512 + tid];
    }
    __syncthreads();

    const int fg = lane >> 4;      // fragment k-group 0..3
    const int fr = lane & 15;      // fragment row 0..15

    const float F0 = fsrc[mb0 * 16 + fr];
    const float F1 = fsrc[mb0 * 16 + 16 + fr];
    const float* ar0 = adj + (size_t)(mb0 * 16 + fr) * NN + (size_t)seg * 512 + fg * 8;
    const float* ar1 = ar0 + (size_t)16 * NN;

    f32x4 acc[2][NBLK];
#pragma unroll
    for (int m = 0; m < 2; ++m)
#pragma unroll
        for (int nb = 0; nb < NBLK; ++nb) acc[m][nb] = (f32x4){0.f, 0.f, 0.f, 0.f};
    float nacc0 = 0.f, nacc1 = 0.f;

    // att + pack -> A-fragment directly (lane already holds its 8 k-values)
    auto mkfrag = [&](f32x4 a0, f32x4 a1, f32x4 e0, f32x4 e1, float F_i,
                      float& nacc) -> short8 {
        float v[8];
#pragma unroll
        for (int t = 0; t < 4; ++t) {
            float sg  = __builtin_amdgcn_rcpf(fmaf(F_i, e0[t], 1.0f));
            float att = sg * a0[t];
            nacc = fmaf(att, att, nacc);
            v[t] = att;
        }
#pragma unroll
        for (int t = 0; t < 4; ++t) {
            float sg  = __builtin_amdgcn_rcpf(fmaf(F_i, e1[t], 1.0f));
            float att = sg * a1[t];
            nacc = fmaf(att, att, nacc);
            v[4 + t] = att;
        }
        i32x4 wv;
        wv[0] = (int)(f2bfu(v[0]) | (f2bfu(v[1]) << 16));
        wv[1] = (int)(f2bfu(v[2]) | (f2bfu(v[3]) << 16));
        wv[2] = (int)(f2bfu(v[4]) | (f2bfu(v[5]) << 16));
        wv[3] = (int)(f2bfu(v[6]) | (f2bfu(v[7]) << 16));
        return *(short8*)&wv;
    };

    // depth-1 software pipeline on all 4 adj loads
    f32x4 c00 = *(const f32x4*)(ar0);
    f32x4 c01 = *(const f32x4*)(ar0 + 4);
    f32x4 c10 = *(const f32x4*)(ar1);
    f32x4 c11 = *(const f32x4*)(ar1 + 4);

    for (int k = 0; k < 16; ++k) {
        f32x4 n00, n01, n10, n11;
        if (k < 15) {
            n00 = *(const f32x4*)(ar0 + (k + 1) * 32);
            n01 = *(const f32x4*)(ar0 + (k + 1) * 32 + 4);
            n10 = *(const f32x4*)(ar1 + (k + 1) * 32);
            n11 = *(const f32x4*)(ar1 + (k + 1) * 32 + 4);
        }
        f32x4 e0 = *(const f32x4*)&Es[k * 32 + fg * 8];
        f32x4 e1 = *(const f32x4*)&Es[k * 32 + fg * 8 + 4];

        short8 af0 = mkfrag(c00, c01, e0, e1, F0, nacc0);
        short8 af1 = mkfrag(c10, c11, e0, e1, F1, nacc1);

#pragma unroll
        for (int nb = 0; nb < NBLK; ++nb) {
            short8 bf = *(const short8*)&Bs[((k * NBLK + nb) * 64 + lane) * 8];
            acc[0][nb] = __builtin_amdgcn_mfma_f32_16x16x32_bf16(af0, bf, acc[0][nb], 0, 0, 0);
            acc[1][nb] = __builtin_amdgcn_mfma_f32_16x16x32_bf16(af1, bf, acc[1][nb], 0, 0, 0);
        }
        c00 = n00; c01 = n01; c10 = n10; c11 = n11;
    }

    // norm partials: lanes {fr, fr+16, fr+32, fr+48} hold row fr pieces
    nacc0 += __shfl_xor(nacc0, 16);
    nacc0 += __shfl_xor(nacc0, 32);
    nacc1 += __shfl_xor(nacc1, 16);
    nacc1 += __shfl_xor(nacc1, 32);
    if (lane < 16) {
        normpart[(mb0 * 16 + lane) * 16 + seg]      = nacc0;
        normpart[(mb0 * 16 + 16 + lane) * 16 + seg] = nacc1;
    }

    // C/D: col = lane&15, row = (lane>>4)*4 + rr
    constexpr int F = NBLK * 16;
#pragma unroll
    for (int m = 0; m < 2; ++m)
#pragma unroll
        for (int nb = 0; nb < NBLK; ++nb)
#pragma unroll
            for (int rr = 0; rr < 4; ++rr)
                outp[((size_t)seg * NN + mb0 * 16 + m * 16 + fg * 4 + rr) * F
                     + nb * 16 + fr] = acc[m][nb][rr];
}

// ---------------------------------------------------------------------------
// R1: h1[i][f] = sum_seg outp1 / (sqrt(sum_p normpart1[i][p]) + 1e-10)
// ---------------------------------------------------------------------------
__global__ __launch_bounds__(256) void r1_kernel(
    const float* __restrict__ outp, const float* __restrict__ normpart,
    float* __restrict__ h1)
{
    int tid = blockIdx.x * 256 + threadIdx.x;
    int i = tid >> 6, f = tid & 63;
    float s = 0.f;
#pragma unroll
    for (int sg = 0; sg < 16; ++sg)
        s += outp[((size_t)sg * NN + i) * 64 + f];
    float n = 0.f;
#pragma unroll
    for (int p = 0; p < 16; ++p) n += normpart[i * 16 + p];
    h1[tid] = s / (sqrtf(n) + 1e-10f);
}

// ---------------------------------------------------------------------------
// P2: z = h1 @ W2, written DIRECTLY as zB fragments (padded cols 10..15 = 0);
// fsrc2/edst2 = exp(-z . a2 halves). Replaces p2 + swizzle2.
// ---------------------------------------------------------------------------
__global__ __launch_bounds__(256) void p2_kernel(
    const float* __restrict__ h1, const float* __restrict__ W2,
    const float* __restrict__ a2, short* __restrict__ zB,
    float* __restrict__ fsrc2, float* __restrict__ edst2)
{
    int i = blockIdx.x * 256 + threadIdx.x;
    if (i >= NN) return;
    float zz[10];
#pragma unroll
    for (int c = 0; c < 10; ++c) zz[c] = 0.f;
    for (int f = 0; f < 64; ++f) {
        float hv = h1[(size_t)i * 64 + f];
#pragma unroll
        for (int c = 0; c < 10; ++c) zz[c] = fmaf(hv, W2[f * 10 + c], zz[c]);
    }
    float s1 = 0.f, s2 = 0.f;
    const int kb   = i >> 5;
    const int rowk = i & 31;
    const int lhi  = (rowk >> 3) << 4;
    const int j    = rowk & 7;
#pragma unroll
    for (int c = 0; c < 10; ++c) {
        s1 = fmaf(zz[c], a2[c], s1);
        s2 = fmaf(zz[c], a2[10 + c], s2);
        zB[((size_t)kb * 64 + (lhi | c)) * 8 + j] = (short)f2bfu(zz[c]);
    }
#pragma unroll
    for (int c = 10; c < 16; ++c)
        zB[((size_t)kb * 64 + (lhi | c)) * 8 + j] = 0;
    fsrc2[i] = expneg(s1);
    edst2[i] = expneg(s2);
}

// ---------------------------------------------------------------------------
// R2: h2 = partials/norm, then log_softmax over 10 classes -> d_out
// ---------------------------------------------------------------------------
__global__ __launch_bounds__(256) void r2_kernel(
    const float* __restrict__ outp, const float* __restrict__ normpart,
    float* __restrict__ out)
{
    int i = blockIdx.x * 256 + threadIdx.x;
    if (i >= NN) return;
    float n = 0.f;
#pragma unroll
    for (int p = 0; p < 16; ++p) n += normpart[i * 16 + p];
    float inv = 1.0f / (sqrtf(n) + 1e-10f);
    float v[10];
    float m = -1e30f;
#pragma unroll
    for (int c = 0; c < 10; ++c) {
        float s = 0.f;
#pragma unroll
        for (int sg = 0; sg < 16; ++sg)
            s += outp[((size_t)sg * NN + i) * 16 + c];
        v[c] = s * inv;
        m = fmaxf(m, v[c]);
    }
    float es = 0.f;
#pragma unroll
    for (int c = 0; c < 10; ++c) es += expf(v[c] - m);
    float lse = m + logf(es);
#pragma unroll
    for (int c = 0; c < 10; ++c) out[(size_t)i * 10 + c] = v[c] - lse;
}

extern "C" void kernel_launch(void* const* d_in, const int* in_sizes, int n_in,
                              void* d_out, int out_size, void* d_ws, size_t ws_size,
                              hipStream_t stream)
{
    const float* x   = (const float*)d_in[0];
    const float* adj = (const float*)d_in[1];
    const float* W1  = (const float*)d_in[2];
    const float* a1  = (const float*)d_in[3];
    const float* W2  = (const float*)d_in[4];
    const float* a2  = (const float*)d_in[5];
    float* out = (float*)d_out;

    char* ws = (char*)d_ws;
    size_t off = 0;
    auto alloc = [&](size_t bytes) -> void* {
        void* p = ws + off;
        off += (bytes + 255) & ~(size_t)255;
        return p;
    };
    float* h      = (float*)alloc((size_t)NN * 64 * 4);
    float* fsrc1  = (float*)alloc((size_t)NN * 4);
    float* edst1  = (float*)alloc((size_t)NN * 4);
    short* hB1    = (short*)alloc((size_t)NN * 64 * 2);
    float* outp1  = (float*)alloc((size_t)16 * NN * 64 * 4);     // 33.5MB
    float* normp1 = (float*)alloc((size_t)NN * 16 * 4);
    float* h1     = (float*)alloc((size_t)NN * 64 * 4);
    float* fsrc2  = (float*)alloc((size_t)NN * 4);
    float* edst2  = (float*)alloc((size_t)NN * 4);
    short* zB     = (short*)alloc((size_t)NN * 16 * 2);
    float* outp2  = (float*)alloc((size_t)16 * NN * 16 * 4);     // 8.4MB
    float* normp2 = (float*)alloc((size_t)NN * 16 * 4);

    hipLaunchKernelGGL(p1_kernel, dim3(NN / 8), dim3(256), 0, stream,
                       x, W1, a1, h, fsrc1, edst1);
    hipLaunchKernelGGL(swizzle_kernel, dim3(2048), dim3(256), 0, stream,
                       h, hB1, 4, 64, NN * 64);
    hipLaunchKernelGGL((fused_kernel<4>), dim3(32, 16), dim3(512), 0, stream,
                       adj, fsrc1, edst1, hB1, outp1, normp1);
    hipLaunchKernelGGL(r1_kernel, dim3(2048), dim3(256), 0, stream,
                       outp1, normp1, h1);
    hipLaunchKernelGGL(p2_kernel, dim3(32), dim3(256), 0, stream,
                       h1, W2, a2, zB, fsrc2, edst2);
    hipLaunchKernelGGL((fused_kernel<1>), dim3(32, 16), dim3(512), 0, stream,
                       adj, fsrc2, edst2, zB, outp2, normp2);
    hipLaunchKernelGGL(r2_kernel, dim3(32), dim3(256), 0, stream,
                       outp2, normp2, out);
}

// Round 16
// 177.343 us; speedup vs baseline: 1.0535x; 1.0535x over previous
//
#include <hip/hip_runtime.h>
#include <hip/hip_bf16.h>
#include <math.h>

typedef __attribute__((ext_vector_type(4))) float f32x4;
typedef __attribute__((ext_vector_type(4))) int   i32x4;
typedef __attribute__((ext_vector_type(8))) short short8;

#define NN 8192
#define LOG2E 1.44269504088896f

// f32 -> bf16 bits, round-to-nearest-even
__device__ __forceinline__ unsigned f2bfu(float x) {
    unsigned u = __float_as_uint(x);
    u += 0x7FFFu + ((u >> 16) & 1u);
    return u >> 16;
}
__device__ __forceinline__ float expneg(float s) {   // exp(-s)
    return __builtin_amdgcn_exp2f(-LOG2E * s);
}

// ---------------------------------------------------------------------------
// P1: h = x @ W1  [8192,500]@[500,64] with W1 staged in LDS. 1024 blocks x
// 8 rows (2 rows/wave) -> 16 waves/CU. Writes fsrc/edst = exp(-h.a halves).
// ---------------------------------------------------------------------------
#define P1_CHUNK 100
__global__ __launch_bounds__(256) void p1_kernel(
    const float* __restrict__ x, const float* __restrict__ W1,
    const float* __restrict__ a1, float* __restrict__ h,
    float* __restrict__ fsrc, float* __restrict__ edst)
{
    __shared__ float wtile[P1_CHUNK * 64];
    const int lane = threadIdx.x & 63;
    const int w    = threadIdx.x >> 6;
    const int r0   = blockIdx.x * 8 + w * 2;

    float acc[2];
    acc[0] = 0.f; acc[1] = 0.f;

    for (int c = 0; c < 5; ++c) {
        const int kb = c * P1_CHUNK;
        __syncthreads();
        for (int idx = threadIdx.x; idx < P1_CHUNK * 64; idx += 256)
            wtile[idx] = W1[kb * 64 + idx];
        __syncthreads();
        for (int kk = 0; kk < P1_CHUNK; kk += 4) {
            float w0 = wtile[(kk + 0) * 64 + lane];
            float w1 = wtile[(kk + 1) * 64 + lane];
            float w2 = wtile[(kk + 2) * 64 + lane];
            float w3 = wtile[(kk + 3) * 64 + lane];
#pragma unroll
            for (int r = 0; r < 2; ++r) {
                f32x4 xv = *(const f32x4*)(x + (size_t)(r0 + r) * 500 + kb + kk);
                acc[r] = fmaf(xv[0], w0, acc[r]);
                acc[r] = fmaf(xv[1], w1, acc[r]);
                acc[r] = fmaf(xv[2], w2, acc[r]);
                acc[r] = fmaf(xv[3], w3, acc[r]);
            }
        }
    }
    float a_s = a1[lane], a_d = a1[64 + lane];
#pragma unroll
    for (int r = 0; r < 2; ++r) {
        h[(size_t)(r0 + r) * 64 + lane] = acc[r];
        float ps = acc[r] * a_s, pd = acc[r] * a_d;
        for (int off = 32; off > 0; off >>= 1) {
            ps += __shfl_down(ps, off); pd += __shfl_down(pd, off);
        }
        if (lane == 0) {
            fsrc[r0 + r] = expneg(ps);
            edst[r0 + r] = expneg(pd);
        }
    }
}

// ---------------------------------------------------------------------------
// Swizzle f32 matrix into bf16 B-fragment order (layer-1 h -> hB):
// hB[kb][nb][lane][i] = bf16( h[kb*32 + (lane>>4)*8 + i][nb*16 + (lane&15)] )
// ---------------------------------------------------------------------------
__global__ __launch_bounds__(256) void swizzle_kernel(
    const float* __restrict__ h, short* __restrict__ hB,
    int nblk, int ncols, int total)
{
    int tid = blockIdx.x * 256 + threadIdx.x;
    if (tid >= total) return;
    int i  = tid & 7;
    int l  = (tid >> 3) & 63;
    int t2 = tid >> 9;
    int nb = t2 % nblk;
    int kb = t2 / nblk;
    int row = kb * 32 + (l >> 4) * 8 + i;
    int col = nb * 16 + (l & 15);
    float v = h[(size_t)row * ncols + col];
    hB[tid] = (short)f2bfu(v);
}

// ---------------------------------------------------------------------------
// FUSED GAT layer, 2 tiles/wave, FULL-LINE LOADS (8x128B per instruction).
// Block = 8 waves x 512 thr, LB(512,4). Wave owns tiles mb0, mb0+1 x seg.
// Load layout: lane (r2=lane>>3, h=lane&7); per k-step per tile TWO loads:
// set0 = adj[row r2][k*32+h*4..+3], set1 = adj[row r2+8][same cols] -- each
// instruction = 8 rows x 128B full lines (HALF the segment count of r14's
// 16x64B). Permute to A-fragment: 8 bpermute + 4 cndmask per tile (same as
// r14). Es read: ONE b128 per k-step shared by both sets AND both tiles.
// NO global stores in the loop (870 GB/s trap).
// ---------------------------------------------------------------------------
template <int NBLK>
__global__ __launch_bounds__(512, 4) void fused_kernel(
    const float* __restrict__ adj, const float* __restrict__ fsrc,
    const float* __restrict__ edst, const short* __restrict__ Bfrag,
    float* __restrict__ outp, float* __restrict__ normpart)
{
    __shared__ __align__(16) short Bs[16 * NBLK * 64 * 8];  // 64KB / 16KB
    __shared__ __align__(16) float Es[512];                 // 2KB
    const int tid  = threadIdx.x;
    const int lane = tid & 63;
    const int w    = tid >> 6;          // 0..7
    const int seg  = blockIdx.y;
    const int mb0  = blockIdx.x * 16 + w * 2;

    {
        const short8* src = (const short8*)(Bfrag) + (size_t)seg * (16 * NBLK * 64);
        short8* dst = (short8*)Bs;
#pragma unroll
        for (int j = 0; j < 2 * NBLK; ++j)
            dst[tid + 512 * j] = src[tid + 512 * j];
        Es[tid] = edst[seg * 512 + tid];
    }
    __syncthreads();

    const int r2 = lane >> 3;      // load-layout row 0..7 (and +8 for set1)
    const int hh = lane & 7;       // load-layout col eighth

    // per-row sigmoid factors for the 4 (tile,set) rows this lane computes
    const float F00 = fsrc[mb0 * 16 + r2];            // tile0 set0
    const float F01 = fsrc[mb0 * 16 + 8 + r2];        // tile0 set1
    const float F10 = fsrc[mb0 * 16 + 16 + r2];       // tile1 set0
    const float F11 = fsrc[mb0 * 16 + 24 + r2];       // tile1 set1

    const float* a00 = adj + (size_t)(mb0 * 16 + r2) * NN + (size_t)seg * 512 + hh * 4;
    const float* a01 = a00 + (size_t)8 * NN;
    const float* a10 = a00 + (size_t)16 * NN;
    const float* a11 = a00 + (size_t)24 * NN;

    // fragment-lane coordinates (destination of the permute)
    const int fg = lane >> 4;
    const int fr = lane & 15;
    const int s0 = (fr & 7) * 8 + fg * 2;   // source lane for dst dwords 0,1
    const int s1 = s0 + 1;                  // source lane for dst dwords 2,3
    const bool lowset = (fr < 8);           // set0 rows 0..7, set1 rows 8..15

    f32x4 acc[2][NBLK];
#pragma unroll
    for (int m = 0; m < 2; ++m)
#pragma unroll
        for (int nb = 0; nb < NBLK; ++nb) acc[m][nb] = (f32x4){0.f, 0.f, 0.f, 0.f};
    float nacc00 = 0.f, nacc01 = 0.f, nacc10 = 0.f, nacc11 = 0.f;

    // att on 4 values; returns packed 2 dwords
    auto attpack = [&](f32x4 a, f32x4 e, float F_i, float& nacc, int& d0, int& d1) {
        float v0, v1, v2, v3;
        {
            float sg = __builtin_amdgcn_rcpf(fmaf(F_i, e[0], 1.0f));
            v0 = sg * a[0]; nacc = fmaf(v0, v0, nacc);
            sg = __builtin_amdgcn_rcpf(fmaf(F_i, e[1], 1.0f));
            v1 = sg * a[1]; nacc = fmaf(v1, v1, nacc);
            sg = __builtin_amdgcn_rcpf(fmaf(F_i, e[2], 1.0f));
            v2 = sg * a[2]; nacc = fmaf(v2, v2, nacc);
            sg = __builtin_amdgcn_rcpf(fmaf(F_i, e[3], 1.0f));
            v3 = sg * a[3]; nacc = fmaf(v3, v3, nacc);
        }
        d0 = (int)(f2bfu(v0) | (f2bfu(v1) << 16));
        d1 = (int)(f2bfu(v2) | (f2bfu(v3) << 16));
    };

    // permute (set0 dwords d0,d1 / set1 dwords e0,e1) -> A-fragment
    auto permute = [&](int d0, int d1, int g0, int g1) -> short8 {
        int p0 = __shfl(d0, s0, 64), p1 = __shfl(d1, s0, 64);
        int p2 = __shfl(d0, s1, 64), p3 = __shfl(d1, s1, 64);
        int q0 = __shfl(g0, s0, 64), q1 = __shfl(g1, s0, 64);
        int q2 = __shfl(g0, s1, 64), q3 = __shfl(g1, s1, 64);
        i32x4 wv;
        wv[0] = lowset ? p0 : q0;
        wv[1] = lowset ? p1 : q1;
        wv[2] = lowset ? p2 : q2;
        wv[3] = lowset ? p3 : q3;
        return *(short8*)&wv;
    };

    // depth-1 software pipeline on all 4 adj loads
    f32x4 c00 = *(const f32x4*)(a00);
    f32x4 c01 = *(const f32x4*)(a01);
    f32x4 c10 = *(const f32x4*)(a10);
    f32x4 c11 = *(const f32x4*)(a11);

    for (int k = 0; k < 16; ++k) {
        f32x4 n00, n01, n10, n11;
        if (k < 15) {
            n00 = *(const f32x4*)(a00 + (k + 1) * 32);
            n01 = *(const f32x4*)(a01 + (k + 1) * 32);
            n10 = *(const f32x4*)(a10 + (k + 1) * 32);
            n11 = *(const f32x4*)(a11 + (k + 1) * 32);
        }
        f32x4 e = *(const f32x4*)&Es[k * 32 + hh * 4];   // shared by all 4

        int d00a, d00b, d01a, d01b, d10a, d10b, d11a, d11b;
        attpack(c00, e, F00, nacc00, d00a, d00b);
        attpack(c01, e, F01, nacc01, d01a, d01b);
        attpack(c10, e, F10, nacc10, d10a, d10b);
        attpack(c11, e, F11, nacc11, d11a, d11b);

        short8 af0 = permute(d00a, d00b, d01a, d01b);
        short8 af1 = permute(d10a, d10b, d11a, d11b);

#pragma unroll
        for (int nb = 0; nb < NBLK; ++nb) {
            short8 bf = *(const short8*)&Bs[((k * NBLK + nb) * 64 + lane) * 8];
            acc[0][nb] = __builtin_amdgcn_mfma_f32_16x16x32_bf16(af0, bf, acc[0][nb], 0, 0, 0);
            acc[1][nb] = __builtin_amdgcn_mfma_f32_16x16x32_bf16(af1, bf, acc[1][nb], 0, 0, 0);
        }
        c00 = n00; c01 = n01; c10 = n10; c11 = n11;
    }

    // norm partials: row r2's pieces live in lanes r2*8 + h (h=0..7)
    nacc00 += __shfl_xor(nacc00, 1); nacc00 += __shfl_xor(nacc00, 2);
    nacc00 += __shfl_xor(nacc00, 4);
    nacc01 += __shfl_xor(nacc01, 1); nacc01 += __shfl_xor(nacc01, 2);
    nacc01 += __shfl_xor(nacc01, 4);
    nacc10 += __shfl_xor(nacc10, 1); nacc10 += __shfl_xor(nacc10, 2);
    nacc10 += __shfl_xor(nacc10, 4);
    nacc11 += __shfl_xor(nacc11, 1); nacc11 += __shfl_xor(nacc11, 2);
    nacc11 += __shfl_xor(nacc11, 4);
    if (hh == 0) {
        normpart[(mb0 * 16 + r2) * 16 + seg]      = nacc00;
        normpart[(mb0 * 16 + 8 + r2) * 16 + seg]  = nacc01;
        normpart[(mb0 * 16 + 16 + r2) * 16 + seg] = nacc10;
        normpart[(mb0 * 16 + 24 + r2) * 16 + seg] = nacc11;
    }

    // C/D: col = lane&15, row = (lane>>4)*4 + rr
    constexpr int F = NBLK * 16;
#pragma unroll
    for (int m = 0; m < 2; ++m)
#pragma unroll
        for (int nb = 0; nb < NBLK; ++nb)
#pragma unroll
            for (int rr = 0; rr < 4; ++rr)
                outp[((size_t)seg * NN + mb0 * 16 + m * 16 + fg * 4 + rr) * F
                     + nb * 16 + fr] = acc[m][nb][rr];
}

// ---------------------------------------------------------------------------
// R1: h1[i][f] = sum_seg outp1 / (sqrt(sum_p normpart1[i][p]) + 1e-10)
// ---------------------------------------------------------------------------
__global__ __launch_bounds__(256) void r1_kernel(
    const float* __restrict__ outp, const float* __restrict__ normpart,
    float* __restrict__ h1)
{
    int tid = blockIdx.x * 256 + threadIdx.x;
    int i = tid >> 6, f = tid & 63;
    float s = 0.f;
#pragma unroll
    for (int sg = 0; sg < 16; ++sg)
        s += outp[((size_t)sg * NN + i) * 64 + f];
    float n = 0.f;
#pragma unroll
    for (int p = 0; p < 16; ++p) n += normpart[i * 16 + p];
    h1[tid] = s / (sqrtf(n) + 1e-10f);
}

// ---------------------------------------------------------------------------
// P2: z = h1 @ W2, written DIRECTLY as zB fragments (padded cols 10..15 = 0);
// fsrc2/edst2 = exp(-z . a2 halves). Replaces p2 + swizzle2.
// ---------------------------------------------------------------------------
__global__ __launch_bounds__(256) void p2_kernel(
    const float* __restrict__ h1, const float* __restrict__ W2,
    const float* __restrict__ a2, short* __restrict__ zB,
    float* __restrict__ fsrc2, float* __restrict__ edst2)
{
    int i = blockIdx.x * 256 + threadIdx.x;
    if (i >= NN) return;
    float zz[10];
#pragma unroll
    for (int c = 0; c < 10; ++c) zz[c] = 0.f;
    for (int f = 0; f < 64; ++f) {
        float hv = h1[(size_t)i * 64 + f];
#pragma unroll
        for (int c = 0; c < 10; ++c) zz[c] = fmaf(hv, W2[f * 10 + c], zz[c]);
    }
    float s1 = 0.f, s2 = 0.f;
    const int kb   = i >> 5;
    const int rowk = i & 31;
    const int lhi  = (rowk >> 3) << 4;
    const int j    = rowk & 7;
#pragma unroll
    for (int c = 0; c < 10; ++c) {
        s1 = fmaf(zz[c], a2[c], s1);
        s2 = fmaf(zz[c], a2[10 + c], s2);
        zB[((size_t)kb * 64 + (lhi | c)) * 8 + j] = (short)f2bfu(zz[c]);
    }
#pragma unroll
    for (int c = 10; c < 16; ++c)
        zB[((size_t)kb * 64 + (lhi | c)) * 8 + j] = 0;
    fsrc2[i] = expneg(s1);
    edst2[i] = expneg(s2);
}

// ---------------------------------------------------------------------------
// R2: h2 = partials/norm, then log_softmax over 10 classes -> d_out
// ---------------------------------------------------------------------------
__global__ __launch_bounds__(256) void r2_kernel(
    const float* __restrict__ outp, const float* __restrict__ normpart,
    float* __restrict__ out)
{
    int i = blockIdx.x * 256 + threadIdx.x;
    if (i >= NN) return;
    float n = 0.f;
#pragma unroll
    for (int p = 0; p < 16; ++p) n += normpart[i * 16 + p];
    float inv = 1.0f / (sqrtf(n) + 1e-10f);
    float v[10];
    float m = -1e30f;
#pragma unroll
    for (int c = 0; c < 10; ++c) {
        float s = 0.f;
#pragma unroll
        for (int sg = 0; sg < 16; ++sg)
            s += outp[((size_t)sg * NN + i) * 16 + c];
        v[c] = s * inv;
        m = fmaxf(m, v[c]);
    }
    float es = 0.f;
#pragma unroll
    for (int c = 0; c < 10; ++c) es += expf(v[c] - m);
    float lse = m + logf(es);
#pragma unroll
    for (int c = 0; c < 10; ++c) out[(size_t)i * 10 + c] = v[c] - lse;
}

extern "C" void kernel_launch(void* const* d_in, const int* in_sizes, int n_in,
                              void* d_out, int out_size, void* d_ws, size_t ws_size,
                              hipStream_t stream)
{
    const float* x   = (const float*)d_in[0];
    const float* adj = (const float*)d_in[1];
    const float* W1  = (const float*)d_in[2];
    const float* a1  = (const float*)d_in[3];
    const float* W2  = (const float*)d_in[4];
    const float* a2  = (const float*)d_in[5];
    float* out = (float*)d_out;

    char* ws = (char*)d_ws;
    size_t off = 0;
    auto alloc = [&](size_t bytes) -> void* {
        void* p = ws + off;
        off += (bytes + 255) & ~(size_t)255;
        return p;
    };
    float* h      = (float*)alloc((size_t)NN * 64 * 4);
    float* fsrc1  = (float*)alloc((size_t)NN * 4);
    float* edst1  = (float*)alloc((size_t)NN * 4);
    short* hB1    = (short*)alloc((size_t)NN * 64 * 2);
    float* outp1  = (float*)alloc((size_t)16 * NN * 64 * 4);     // 33.5MB
    float* normp1 = (float*)alloc((size_t)NN * 16 * 4);
    float* h1     = (float*)alloc((size_t)NN * 64 * 4);
    float* fsrc2  = (float*)alloc((size_t)NN * 4);
    float* edst2  = (float*)alloc((size_t)NN * 4);
    short* zB     = (short*)alloc((size_t)NN * 16 * 2);
    float* outp2  = (float*)alloc((size_t)16 * NN * 16 * 4);     // 8.4MB
    float* normp2 = (float*)alloc((size_t)NN * 16 * 4);

    hipLaunchKernelGGL(p1_kernel, dim3(NN / 8), dim3(256), 0, stream,
                       x, W1, a1, h, fsrc1, edst1);
    hipLaunchKernelGGL(swizzle_kernel, dim3(2048), dim3(256), 0, stream,
                       h, hB1, 4, 64, NN * 64);
    hipLaunchKernelGGL((fused_kernel<4>), dim3(32, 16), dim3(512), 0, stream,
                       adj, fsrc1, edst1, hB1, outp1, normp1);
    hipLaunchKernelGGL(r1_kernel, dim3(2048), dim3(256), 0, stream,
                       outp1, normp1, h1);
    hipLaunchKernelGGL(p2_kernel, dim3(32), dim3(256), 0, stream,
                       h1, W2, a2, zB, fsrc2, edst2);
    hipLaunchKernelGGL((fused_kernel<1>), dim3(32, 16), dim3(512), 0, stream,
                       adj, fsrc2, edst2, zB, outp2, normp2);
    hipLaunchKernelGGL(r2_kernel, dim3(32), dim3(256), 0, stream,
                       outp2, normp2, out);
}

// Round 17
// 171.798 us; speedup vs baseline: 1.0875x; 1.0323x over previous
//
#include <hip/hip_runtime.h>
#include <hip/hip_bf16.h>
#include <math.h>

typedef __attribute__((ext_vector_type(4))) float f32x4;
typedef __attribute__((ext_vector_type(4))) int   i32x4;
typedef __attribute__((ext_vector_type(8))) short short8;

#define NN 8192
#define LOG2E 1.44269504088896f

// f32 -> bf16 bits, round-to-nearest-even
__device__ __forceinline__ unsigned f2bfu(float x) {
    unsigned u = __float_as_uint(x);
    u += 0x7FFFu + ((u >> 16) & 1u);
    return u >> 16;
}
__device__ __forceinline__ float expneg(float s) {   // exp(-s)
    return __builtin_amdgcn_exp2f(-LOG2E * s);
}

// ---------------------------------------------------------------------------
// P1: h = x @ W1  [8192,500]@[500,64] with W1 staged in LDS. 1024 blocks x
// 8 rows (2 rows/wave) -> 16 waves/CU. Writes fsrc/edst = exp(-h.a halves).
// ---------------------------------------------------------------------------
#define P1_CHUNK 100
__global__ __launch_bounds__(256) void p1_kernel(
    const float* __restrict__ x, const float* __restrict__ W1,
    const float* __restrict__ a1, float* __restrict__ h,
    float* __restrict__ fsrc, float* __restrict__ edst)
{
    __shared__ float wtile[P1_CHUNK * 64];
    const int lane = threadIdx.x & 63;
    const int w    = threadIdx.x >> 6;
    const int r0   = blockIdx.x * 8 + w * 2;

    float acc[2];
    acc[0] = 0.f; acc[1] = 0.f;

    for (int c = 0; c < 5; ++c) {
        const int kb = c * P1_CHUNK;
        __syncthreads();
        for (int idx = threadIdx.x; idx < P1_CHUNK * 64; idx += 256)
            wtile[idx] = W1[kb * 64 + idx];
        __syncthreads();
        for (int kk = 0; kk < P1_CHUNK; kk += 4) {
            float w0 = wtile[(kk + 0) * 64 + lane];
            float w1 = wtile[(kk + 1) * 64 + lane];
            float w2 = wtile[(kk + 2) * 64 + lane];
            float w3 = wtile[(kk + 3) * 64 + lane];
#pragma unroll
            for (int r = 0; r < 2; ++r) {
                f32x4 xv = *(const f32x4*)(x + (size_t)(r0 + r) * 500 + kb + kk);
                acc[r] = fmaf(xv[0], w0, acc[r]);
                acc[r] = fmaf(xv[1], w1, acc[r]);
                acc[r] = fmaf(xv[2], w2, acc[r]);
                acc[r] = fmaf(xv[3], w3, acc[r]);
            }
        }
    }
    float a_s = a1[lane], a_d = a1[64 + lane];
#pragma unroll
    for (int r = 0; r < 2; ++r) {
        h[(size_t)(r0 + r) * 64 + lane] = acc[r];
        float ps = acc[r] * a_s, pd = acc[r] * a_d;
        for (int off = 32; off > 0; off >>= 1) {
            ps += __shfl_down(ps, off); pd += __shfl_down(pd, off);
        }
        if (lane == 0) {
            fsrc[r0 + r] = expneg(ps);
            edst[r0 + r] = expneg(pd);
        }
    }
}

// ---------------------------------------------------------------------------
// Swizzle f32 matrix into bf16 B-fragment order (layer-1 h -> hB):
// hB[kb][nb][lane][i] = bf16( h[kb*32 + (lane>>4)*8 + i][nb*16 + (lane&15)] )
// ---------------------------------------------------------------------------
__global__ __launch_bounds__(256) void swizzle_kernel(
    const float* __restrict__ h, short* __restrict__ hB,
    int nblk, int ncols, int total)
{
    int tid = blockIdx.x * 256 + threadIdx.x;
    if (tid >= total) return;
    int i  = tid & 7;
    int l  = (tid >> 3) & 63;
    int t2 = tid >> 9;
    int nb = t2 % nblk;
    int kb = t2 / nblk;
    int row = kb * 32 + (l >> 4) * 8 + i;
    int col = nb * 16 + (l & 15);
    float v = h[(size_t)row * ncols + col];
    hB[tid] = (short)f2bfu(v);
}

// ---------------------------------------------------------------------------
// FUSED GAT layer, 2 tiles/wave, full-line loads + K-PHASE ROTATION.
// Block = 8 waves x 512 thr, LB(512,4). Wave owns tiles mb0, mb0+1 x seg.
// Each wave starts its k-loop at phase=(2w+bx)&15 and walks k cyclically:
// de-correlates the grid's instantaneous column window (DRAM channel/page
// hotspot fix). MFMA accumulation is k-order-independent; Es/Bs indexed by
// the rotated k. Depth-1 prefetch follows the rotation.
// NO global stores in the loop (870 GB/s trap).
// ---------------------------------------------------------------------------
template <int NBLK>
__global__ __launch_bounds__(512, 4) void fused_kernel(
    const float* __restrict__ adj, const float* __restrict__ fsrc,
    const float* __restrict__ edst, const short* __restrict__ Bfrag,
    float* __restrict__ outp, float* __restrict__ normpart)
{
    __shared__ __align__(16) short Bs[16 * NBLK * 64 * 8];  // 64KB / 16KB
    __shared__ __align__(16) float Es[512];                 // 2KB
    const int tid  = threadIdx.x;
    const int lane = tid & 63;
    const int w    = tid >> 6;          // 0..7
    const int seg  = blockIdx.y;
    const int mb0  = blockIdx.x * 16 + w * 2;

    {
        const short8* src = (const short8*)(Bfrag) + (size_t)seg * (16 * NBLK * 64);
        short8* dst = (short8*)Bs;
#pragma unroll
        for (int j = 0; j < 2 * NBLK; ++j)
            dst[tid + 512 * j] = src[tid + 512 * j];
        Es[tid] = edst[seg * 512 + tid];
    }
    __syncthreads();

    const int r2 = lane >> 3;      // load-layout row 0..7 (and +8 for set1)
    const int hh = lane & 7;       // load-layout col eighth

    const float F00 = fsrc[mb0 * 16 + r2];
    const float F01 = fsrc[mb0 * 16 + 8 + r2];
    const float F10 = fsrc[mb0 * 16 + 16 + r2];
    const float F11 = fsrc[mb0 * 16 + 24 + r2];

    const float* a00 = adj + (size_t)(mb0 * 16 + r2) * NN + (size_t)seg * 512 + hh * 4;
    const float* a01 = a00 + (size_t)8 * NN;
    const float* a10 = a00 + (size_t)16 * NN;
    const float* a11 = a00 + (size_t)24 * NN;

    // fragment-lane coordinates (destination of the permute)
    const int fg = lane >> 4;
    const int fr = lane & 15;
    const int s0 = (fr & 7) * 8 + fg * 2;
    const int s1 = s0 + 1;
    const bool lowset = (fr < 8);

    f32x4 acc[2][NBLK];
#pragma unroll
    for (int m = 0; m < 2; ++m)
#pragma unroll
        for (int nb = 0; nb < NBLK; ++nb) acc[m][nb] = (f32x4){0.f, 0.f, 0.f, 0.f};
    float nacc00 = 0.f, nacc01 = 0.f, nacc10 = 0.f, nacc11 = 0.f;

    auto attpack = [&](f32x4 a, f32x4 e, float F_i, float& nacc, int& d0, int& d1) {
        float v0, v1, v2, v3;
        {
            float sg = __builtin_amdgcn_rcpf(fmaf(F_i, e[0], 1.0f));
            v0 = sg * a[0]; nacc = fmaf(v0, v0, nacc);
            sg = __builtin_amdgcn_rcpf(fmaf(F_i, e[1], 1.0f));
            v1 = sg * a[1]; nacc = fmaf(v1, v1, nacc);
            sg = __builtin_amdgcn_rcpf(fmaf(F_i, e[2], 1.0f));
            v2 = sg * a[2]; nacc = fmaf(v2, v2, nacc);
            sg = __builtin_amdgcn_rcpf(fmaf(F_i, e[3], 1.0f));
            v3 = sg * a[3]; nacc = fmaf(v3, v3, nacc);
        }
        d0 = (int)(f2bfu(v0) | (f2bfu(v1) << 16));
        d1 = (int)(f2bfu(v2) | (f2bfu(v3) << 16));
    };

    auto permute = [&](int d0, int d1, int g0, int g1) -> short8 {
        int p0 = __shfl(d0, s0, 64), p1 = __shfl(d1, s0, 64);
        int p2 = __shfl(d0, s1, 64), p3 = __shfl(d1, s1, 64);
        int q0 = __shfl(g0, s0, 64), q1 = __shfl(g1, s0, 64);
        int q2 = __shfl(g0, s1, 64), q3 = __shfl(g1, s1, 64);
        i32x4 wv;
        wv[0] = lowset ? p0 : q0;
        wv[1] = lowset ? p1 : q1;
        wv[2] = lowset ? p2 : q2;
        wv[3] = lowset ? p3 : q3;
        return *(short8*)&wv;
    };

    // k-phase rotation: start at (2w + bx) & 15, walk cyclically
    const int phase = ((w << 1) + blockIdx.x) & 15;
    int kcur = phase;

    // depth-1 software pipeline on all 4 adj loads (rotated order)
    f32x4 c00 = *(const f32x4*)(a00 + kcur * 32);
    f32x4 c01 = *(const f32x4*)(a01 + kcur * 32);
    f32x4 c10 = *(const f32x4*)(a10 + kcur * 32);
    f32x4 c11 = *(const f32x4*)(a11 + kcur * 32);

    for (int j = 0; j < 16; ++j) {
        const int knext = (kcur + 1) & 15;
        f32x4 n00, n01, n10, n11;
        if (j < 15) {
            n00 = *(const f32x4*)(a00 + knext * 32);
            n01 = *(const f32x4*)(a01 + knext * 32);
            n10 = *(const f32x4*)(a10 + knext * 32);
            n11 = *(const f32x4*)(a11 + knext * 32);
        }
        f32x4 e = *(const f32x4*)&Es[kcur * 32 + hh * 4];   // shared by all 4

        int d00a, d00b, d01a, d01b, d10a, d10b, d11a, d11b;
        attpack(c00, e, F00, nacc00, d00a, d00b);
        attpack(c01, e, F01, nacc01, d01a, d01b);
        attpack(c10, e, F10, nacc10, d10a, d10b);
        attpack(c11, e, F11, nacc11, d11a, d11b);

        short8 af0 = permute(d00a, d00b, d01a, d01b);
        short8 af1 = permute(d10a, d10b, d11a, d11b);

#pragma unroll
        for (int nb = 0; nb < NBLK; ++nb) {
            short8 bf = *(const short8*)&Bs[((kcur * NBLK + nb) * 64 + lane) * 8];
            acc[0][nb] = __builtin_amdgcn_mfma_f32_16x16x32_bf16(af0, bf, acc[0][nb], 0, 0, 0);
            acc[1][nb] = __builtin_amdgcn_mfma_f32_16x16x32_bf16(af1, bf, acc[1][nb], 0, 0, 0);
        }
        c00 = n00; c01 = n01; c10 = n10; c11 = n11;
        kcur = knext;
    }

    // norm partials: row r2's pieces live in lanes r2*8 + h (h=0..7)
    nacc00 += __shfl_xor(nacc00, 1); nacc00 += __shfl_xor(nacc00, 2);
    nacc00 += __shfl_xor(nacc00, 4);
    nacc01 += __shfl_xor(nacc01, 1); nacc01 += __shfl_xor(nacc01, 2);
    nacc01 += __shfl_xor(nacc01, 4);
    nacc10 += __shfl_xor(nacc10, 1); nacc10 += __shfl_xor(nacc10, 2);
    nacc10 += __shfl_xor(nacc10, 4);
    nacc11 += __shfl_xor(nacc11, 1); nacc11 += __shfl_xor(nacc11, 2);
    nacc11 += __shfl_xor(nacc11, 4);
    if (hh == 0) {
        normpart[(mb0 * 16 + r2) * 16 + seg]      = nacc00;
        normpart[(mb0 * 16 + 8 + r2) * 16 + seg]  = nacc01;
        normpart[(mb0 * 16 + 16 + r2) * 16 + seg] = nacc10;
        normpart[(mb0 * 16 + 24 + r2) * 16 + seg] = nacc11;
    }

    // C/D: col = lane&15, row = (lane>>4)*4 + rr
    constexpr int F = NBLK * 16;
#pragma unroll
    for (int m = 0; m < 2; ++m)
#pragma unroll
        for (int nb = 0; nb < NBLK; ++nb)
#pragma unroll
            for (int rr = 0; rr < 4; ++rr)
                outp[((size_t)seg * NN + mb0 * 16 + m * 16 + fg * 4 + rr) * F
                     + nb * 16 + fr] = acc[m][nb][rr];
}

// ---------------------------------------------------------------------------
// R1: h1[i][f] = sum_seg outp1 / (sqrt(sum_p normpart1[i][p]) + 1e-10)
// ---------------------------------------------------------------------------
__global__ __launch_bounds__(256) void r1_kernel(
    const float* __restrict__ outp, const float* __restrict__ normpart,
    float* __restrict__ h1)
{
    int tid = blockIdx.x * 256 + threadIdx.x;
    int i = tid >> 6, f = tid & 63;
    float s = 0.f;
#pragma unroll
    for (int sg = 0; sg < 16; ++sg)
        s += outp[((size_t)sg * NN + i) * 64 + f];
    float n = 0.f;
#pragma unroll
    for (int p = 0; p < 16; ++p) n += normpart[i * 16 + p];
    h1[tid] = s / (sqrtf(n) + 1e-10f);
}

// ---------------------------------------------------------------------------
// P2: z = h1 @ W2, written DIRECTLY as zB fragments (padded cols 10..15 = 0);
// fsrc2/edst2 = exp(-z . a2 halves). Replaces p2 + swizzle2.
// ---------------------------------------------------------------------------
__global__ __launch_bounds__(256) void p2_kernel(
    const float* __restrict__ h1, const float* __restrict__ W2,
    const float* __restrict__ a2, short* __restrict__ zB,
    float* __restrict__ fsrc2, float* __restrict__ edst2)
{
    int i = blockIdx.x * 256 + threadIdx.x;
    if (i >= NN) return;
    float zz[10];
#pragma unroll
    for (int c = 0; c < 10; ++c) zz[c] = 0.f;
    for (int f = 0; f < 64; ++f) {
        float hv = h1[(size_t)i * 64 + f];
#pragma unroll
        for (int c = 0; c < 10; ++c) zz[c] = fmaf(hv, W2[f * 10 + c], zz[c]);
    }
    float s1 = 0.f, s2 = 0.f;
    const int kb   = i >> 5;
    const int rowk = i & 31;
    const int lhi  = (rowk >> 3) << 4;
    const int j    = rowk & 7;
#pragma unroll
    for (int c = 0; c < 10; ++c) {
        s1 = fmaf(zz[c], a2[c], s1);
        s2 = fmaf(zz[c], a2[10 + c], s2);
        zB[((size_t)kb * 64 + (lhi | c)) * 8 + j] = (short)f2bfu(zz[c]);
    }
#pragma unroll
    for (int c = 10; c < 16; ++c)
        zB[((size_t)kb * 64 + (lhi | c)) * 8 + j] = 0;
    fsrc2[i] = expneg(s1);
    edst2[i] = expneg(s2);
}

// ---------------------------------------------------------------------------
// R2: h2 = partials/norm, then log_softmax over 10 classes -> d_out
// ---------------------------------------------------------------------------
__global__ __launch_bounds__(256) void r2_kernel(
    const float* __restrict__ outp, const float* __restrict__ normpart,
    float* __restrict__ out)
{
    int i = blockIdx.x * 256 + threadIdx.x;
    if (i >= NN) return;
    float n = 0.f;
#pragma unroll
    for (int p = 0; p < 16; ++p) n += normpart[i * 16 + p];
    float inv = 1.0f / (sqrtf(n) + 1e-10f);
    float v[10];
    float m = -1e30f;
#pragma unroll
    for (int c = 0; c < 10; ++c) {
        float s = 0.f;
#pragma unroll
        for (int sg = 0; sg < 16; ++sg)
            s += outp[((size_t)sg * NN + i) * 16 + c];
        v[c] = s * inv;
        m = fmaxf(m, v[c]);
    }
    float es = 0.f;
#pragma unroll
    for (int c = 0; c < 10; ++c) es += expf(v[c] - m);
    float lse = m + logf(es);
#pragma unroll
    for (int c = 0; c < 10; ++c) out[(size_t)i * 10 + c] = v[c] - lse;
}

extern "C" void kernel_launch(void* const* d_in, const int* in_sizes, int n_in,
                              void* d_out, int out_size, void* d_ws, size_t ws_size,
                              hipStream_t stream)
{
    const float* x   = (const float*)d_in[0];
    const float* adj = (const float*)d_in[1];
    const float* W1  = (const float*)d_in[2];
    const float* a1  = (const float*)d_in[3];
    const float* W2  = (const float*)d_in[4];
    const float* a2  = (const float*)d_in[5];
    float* out = (float*)d_out;

    char* ws = (char*)d_ws;
    size_t off = 0;
    auto alloc = [&](size_t bytes) -> void* {
        void* p = ws + off;
        off += (bytes + 255) & ~(size_t)255;
        return p;
    };
    float* h      = (float*)alloc((size_t)NN * 64 * 4);
    float* fsrc1  = (float*)alloc((size_t)NN * 4);
    float* edst1  = (float*)alloc((size_t)NN * 4);
    short* hB1    = (short*)alloc((size_t)NN * 64 * 2);
    float* outp1  = (float*)alloc((size_t)16 * NN * 64 * 4);     // 33.5MB
    float* normp1 = (float*)alloc((size_t)NN * 16 * 4);
    float* h1     = (float*)alloc((size_t)NN * 64 * 4);
    float* fsrc2  = (float*)alloc((size_t)NN * 4);
    float* edst2  = (float*)alloc((size_t)NN * 4);
    short* zB     = (short*)alloc((size_t)NN * 16 * 2);
    float* outp2  = (float*)alloc((size_t)16 * NN * 16 * 4);     // 8.4MB
    float* normp2 = (float*)alloc((size_t)NN * 16 * 4);

    hipLaunchKernelGGL(p1_kernel, dim3(NN / 8), dim3(256), 0, stream,
                       x, W1, a1, h, fsrc1, edst1);
    hipLaunchKernelGGL(swizzle_kernel, dim3(2048), dim3(256), 0, stream,
                       h, hB1, 4, 64, NN * 64);
    hipLaunchKernelGGL((fused_kernel<4>), dim3(32, 16), dim3(512), 0, stream,
                       adj, fsrc1, edst1, hB1, outp1, normp1);
    hipLaunchKernelGGL(r1_kernel, dim3(2048), dim3(256), 0, stream,
                       outp1, normp1, h1);
    hipLaunchKernelGGL(p2_kernel, dim3(32), dim3(256), 0, stream,
                       h1, W2, a2, zB, fsrc2, edst2);
    hipLaunchKernelGGL((fused_kernel<1>), dim3(32, 16), dim3(512), 0, stream,
                       adj, fsrc2, edst2, zB, outp2, normp2);
    hipLaunchKernelGGL(r2_kernel, dim3(32), dim3(256), 0, stream,
                       outp2, normp2, out);
}